// Round 3
// baseline (145.623 us; speedup 1.0000x reference)
//
#include <hip/hip_runtime.h>
#include <hip/hip_bf16.h>

typedef __attribute__((ext_vector_type(8))) short bf16x8;
typedef __attribute__((ext_vector_type(4))) float f32x4;
typedef __attribute__((ext_vector_type(4))) unsigned short u16x4;
typedef unsigned short u16;

#define M_DIM 50176
#define N_DIM 768
#define K_DIM 768

__device__ __forceinline__ u16 f2bf(float f) {
    __hip_bfloat16 h = __float2bfloat16(f);
    return *reinterpret_cast<u16*>(&h);
}

__device__ __forceinline__ void gld_lds16(const void* g, void* l) {
    __builtin_amdgcn_global_load_lds(
        (const __attribute__((address_space(1))) unsigned int*)g,
        (__attribute__((address_space(3))) unsigned int*)l, 16, 0, 0);
}

// ---------------- Kernel 1: fold weights ----------------
__global__ void fold_weights(const float* __restrict__ qkv_w,
                             const float* __restrict__ qkv_b,
                             const float* __restrict__ proj_w,
                             const float* __restrict__ proj_b,
                             const float* __restrict__ pe,
                             u16* __restrict__ Bw, float* __restrict__ bias) {
    const int o = blockIdx.x;
    const int t = threadIdx.x;
    __shared__ float wv[16];
    __shared__ float bv4[4];
    __shared__ float red[4];
    if (t < 16) wv[t] = qkv_w[32 + t];
    if (t < 4)  bv4[t] = qkv_b[8 + t];
    __syncthreads();
    const float* Prow = proj_w + o * 768;
    float s = 0.f;
    for (int c = t; c < 768; c += 256) {
        int g4 = c & ~3, j = c & 3;
        float af = Prow[g4 + 0] * wv[0 * 4 + j] + Prow[g4 + 1] * wv[1 * 4 + j] +
                   Prow[g4 + 2] * wv[2 * 4 + j] + Prow[g4 + 3] * wv[3 * 4 + j];
        Bw[o * 768 + c] = f2bf(af);
        s += af * pe[c];
        s += Prow[c] * bv4[j];
    }
    #pragma unroll
    for (int off = 32; off; off >>= 1) s += __shfl_down(s, off, 64);
    if ((t & 63) == 0) red[t >> 6] = s;
    __syncthreads();
    if (t == 0) bias[o] = red[0] + red[1] + red[2] + red[3] + proj_b[o];
}

// ---------------- Kernel 2: fused GEMM ----------------
// Y[m,o] = sum_c bf16(X[m,c]) * Bw[o,c] + bias[o]
// 128x128 tile, BK=64, 4 waves (2x2). A: depth-3 reg pipeline -> swizzled LDS (2 bufs).
// B: gld_lds staged 2 tiles ahead into TRIPLE-buffered swizzled LDS.
// Barriers: counted vmcnt (steady-state 20) + lgkmcnt(0) + raw s_barrier.
__global__ __launch_bounds__(256, 2)
void gemm_fused(const float* __restrict__ X, const u16* __restrict__ Bw,
                const float* __restrict__ bias, float* __restrict__ Y) {
    // XCD-aware bijective swizzle: 2352 blocks = 8 * 294
    const int b = blockIdx.x;
    const int bid = (b & 7) * 294 + (b >> 3);
    const int mt = bid / 6, nt = bid - mt * 6;
    const int m0 = mt * 128, n0 = nt * 128;

    const int tid = threadIdx.x;
    const int lane = tid & 63;
    const int w = tid >> 6;
    const int wm = w >> 1, wn = w & 1;

    // LDS: logical [row][kb 0..127 bytes], physical byte = kb ^ ((row&7)<<4)
    __shared__ u16 As[2][128 * 64];
    __shared__ u16 Bs[3][128 * 64];

    f32x4 acc[4][4];
    #pragma unroll
    for (int i = 0; i < 4; ++i)
        #pragma unroll
        for (int j = 0; j < 4; ++j)
            acc[i][j] = (f32x4){0.f, 0.f, 0.f, 0.f};

    const int arow = tid >> 4;      // 0..15
    const int agg  = tid & 15;      // 16B fp32 granule within row
    const int bg = lane & 7;

    float4 R0v[8], R1v[8], R2v[8];

    auto load_a = [&](float4 (&p)[8], int k0) {
        const float4* src = (const float4*)(X + (long)m0 * K_DIM + k0);
        #pragma unroll
        for (int i = 0; i < 8; ++i) {
            int r = arow + 16 * i;
            p[i] = src[(long)r * (K_DIM / 4) + agg];
        }
    };

    auto write_a = [&](int buf, const float4 (&p)[8]) {
        #pragma unroll
        for (int i = 0; i < 8; ++i) {
            int r = arow + 16 * i;
            int pb = (agg * 8) ^ ((r & 7) << 4);   // bf16 byte offset in row
            u16x4 hv;
            hv.x = f2bf(p[i].x);
            hv.y = f2bf(p[i].y);
            hv.z = f2bf(p[i].z);
            hv.w = f2bf(p[i].w);
            *(u16x4*)&As[buf][r * 64 + (pb >> 1)] = hv;
        }
    };

    auto stage_b = [&](int buf, int k0) {
        #pragma unroll
        for (int j = 0; j < 4; ++j) {
            int rowbase = j * 32 + w * 8;
            int row = rowbase + (lane >> 3);
            // pre-swizzled global source, linear LDS dest (base + lane*16)
            const char* src = (const char*)Bw + ((long)(n0 + row) * K_DIM + k0) * 2 +
                              ((bg * 16) ^ ((row & 7) << 4));
            gld_lds16(src, (void*)&Bs[buf][rowbase * 64]);
        }
    };

    auto compute = [&](int ab, int bb) {
        #pragma unroll
        for (int h = 0; h < 2; ++h) {
            bf16x8 av[4], bv_[4];
            #pragma unroll
            for (int mf = 0; mf < 4; ++mf) {
                int r = wm * 64 + mf * 16 + (lane & 15);
                int pb = (h * 64 + ((lane >> 4) << 4)) ^ ((r & 7) << 4);
                av[mf] = *(const bf16x8*)&As[ab][r * 64 + (pb >> 1)];
            }
            #pragma unroll
            for (int nf = 0; nf < 4; ++nf) {
                int r = wn * 64 + nf * 16 + (lane & 15);
                int pb = (h * 64 + ((lane >> 4) << 4)) ^ ((r & 7) << 4);
                bv_[nf] = *(const bf16x8*)&Bs[bb][r * 64 + (pb >> 1)];
            }
            __builtin_amdgcn_s_setprio(1);
            #pragma unroll
            for (int mf = 0; mf < 4; ++mf)
                #pragma unroll
                for (int nf = 0; nf < 4; ++nf)
                    acc[mf][nf] = __builtin_amdgcn_mfma_f32_16x16x32_bf16(
                        av[mf], bv_[nf], acc[mf][nf], 0, 0, 0);
            __builtin_amdgcn_s_setprio(0);
        }
    };

#define BARRIER(VM)                                          \
    __builtin_amdgcn_sched_barrier(0);                       \
    asm volatile("s_waitcnt vmcnt(" VM ") lgkmcnt(0)");      \
    __builtin_amdgcn_s_barrier();                            \
    __builtin_amdgcn_sched_barrier(0);

    // ---- prologue ----
    // vm queue after issues: [R0 8][B0 4][B1 4][R1 8][R2 8]
    load_a(R0v, 0);          // tile0 A
    stage_b(0, 0);           // tile0 B
    stage_b(1, 64);          // tile1 B
    load_a(R1v, 64);         // tile1 A
    load_a(R2v, 128);        // tile2 A
    write_a(0, R0v);         // compiler waits R0 only
    BARRIER("20")            // drain B0; keep B1,R1,R2 (=20) in flight

    // ---- steady iterations t=0..8 ----
    // per iter t: write A(t+1), stage B(t+2), load A(t+3), compute(t)
    // barrier drains B(t+1) (2 iters old), keeps [R(t-1)][B(t+2)][R(t)] = 20
#define ITER_FULL(T, AB, BB, WREG, LREG)                     \
    write_a((AB) ^ 1, WREG);                                 \
    stage_b(((T) + 2) % 3, ((T) + 2) * 64);                  \
    load_a(LREG, ((T) + 3) * 64);                            \
    compute(AB, BB);                                         \
    BARRIER("20")

    ITER_FULL(0, 0, 0, R1v, R0v)
    ITER_FULL(1, 1, 1, R2v, R1v)
    ITER_FULL(2, 0, 2, R0v, R2v)
    ITER_FULL(3, 1, 0, R1v, R0v)
    ITER_FULL(4, 0, 1, R2v, R1v)
    ITER_FULL(5, 1, 2, R0v, R2v)
    ITER_FULL(6, 0, 0, R1v, R0v)
    ITER_FULL(7, 1, 1, R2v, R1v)
    ITER_FULL(8, 0, 2, R0v, R2v)

    // ---- t=9: last stage (tile11), no more A loads ----
    write_a(0, R1v);         // A tile10
    stage_b(2, 11 * 64);     // B tile11
    compute(1, 0);           // tile9
    BARRIER("12")            // queue [B10 4][R_t8 8][B11 4]=16 -> drain B10

    // ---- t=10 ----
    write_a(1, R2v);         // A tile11 (waits R_t8 loads; leaves B11)
    compute(0, 1);           // tile10
    BARRIER("0")             // drain B11

    // ---- t=11 ----
    compute(1, 2);           // tile11 (no barrier needed after)

    // epilogue: C/D layout col=lane&15, row=(lane>>4)*4+reg
    const int colq = lane & 15;
    const int rowq = (lane >> 4) * 4;
    #pragma unroll
    for (int nf = 0; nf < 4; ++nf) {
        int col = n0 + wn * 64 + nf * 16 + colq;
        float bi = bias[col];
        #pragma unroll
        for (int mf = 0; mf < 4; ++mf) {
            long rbase = m0 + wm * 64 + mf * 16 + rowq;
            #pragma unroll
            for (int r = 0; r < 4; ++r) {
                Y[(rbase + r) * N_DIM + col] = acc[mf][nf][r] + bi;
            }
        }
    }
#undef ITER_FULL
#undef BARRIER
}

extern "C" void kernel_launch(void* const* d_in, const int* in_sizes, int n_in,
                              void* d_out, int out_size, void* d_ws, size_t ws_size,
                              hipStream_t stream) {
    const float* x      = (const float*)d_in[0];
    const float* qkv_w  = (const float*)d_in[1];
    const float* qkv_b  = (const float*)d_in[2];
    const float* proj_w = (const float*)d_in[3];
    const float* proj_b = (const float*)d_in[4];
    const float* pe     = (const float*)d_in[5];
    float* y = (float*)d_out;

    u16*   Bw   = (u16*)d_ws;
    float* bias = (float*)((char*)d_ws + (size_t)N_DIM * K_DIM * 2);

    fold_weights<<<768, 256, 0, stream>>>(qkv_w, qkv_b, proj_w, proj_b, pe, Bw, bias);
    gemm_fused<<<(M_DIM / 128) * (N_DIM / 128), 256, 0, stream>>>(x, Bw, bias, y);
}

// Round 4
// 107.383 us; speedup vs baseline: 1.3561x; 1.3561x over previous
//
#include <hip/hip_runtime.h>
#include <hip/hip_bf16.h>

typedef __attribute__((ext_vector_type(8))) short bf16x8;
typedef __attribute__((ext_vector_type(4))) float f32x4;
typedef __attribute__((ext_vector_type(4))) unsigned short u16x4;
typedef unsigned short u16;

#define M_DIM 50176
#define N_DIM 768
#define K_DIM 768

__device__ __forceinline__ u16 f2bf(float f) {
    __hip_bfloat16 h = __float2bfloat16(f);
    return *reinterpret_cast<u16*>(&h);
}

__device__ __forceinline__ void gld_lds16(const void* g, void* l) {
    __builtin_amdgcn_global_load_lds(
        (const __attribute__((address_space(1))) unsigned int*)g,
        (__attribute__((address_space(3))) unsigned int*)l, 16, 0, 0);
}

// ---------------- Kernel 1: fold weights ----------------
__global__ void fold_weights(const float* __restrict__ qkv_w,
                             const float* __restrict__ qkv_b,
                             const float* __restrict__ proj_w,
                             const float* __restrict__ proj_b,
                             const float* __restrict__ pe,
                             u16* __restrict__ Bw, float* __restrict__ bias) {
    const int o = blockIdx.x;
    const int t = threadIdx.x;
    __shared__ float wv[16];
    __shared__ float bv4[4];
    __shared__ float red[4];
    if (t < 16) wv[t] = qkv_w[32 + t];
    if (t < 4)  bv4[t] = qkv_b[8 + t];
    __syncthreads();
    const float* Prow = proj_w + o * 768;
    float s = 0.f;
    for (int c = t; c < 768; c += 256) {
        int g4 = c & ~3, j = c & 3;
        float af = Prow[g4 + 0] * wv[0 * 4 + j] + Prow[g4 + 1] * wv[1 * 4 + j] +
                   Prow[g4 + 2] * wv[2 * 4 + j] + Prow[g4 + 3] * wv[3 * 4 + j];
        Bw[o * 768 + c] = f2bf(af);
        s += af * pe[c];
        s += Prow[c] * bv4[j];
    }
    #pragma unroll
    for (int off = 32; off; off >>= 1) s += __shfl_down(s, off, 64);
    if ((t & 63) == 0) red[t >> 6] = s;
    __syncthreads();
    if (t == 0) bias[o] = red[0] + red[1] + red[2] + red[3] + proj_b[o];
}

// ---------------- Kernel 2: fused GEMM ----------------
// Y[m,o] = sum_c bf16(X[m,c]) * Bw[o,c] + bias[o]
// m97-exact structure: 128x128 tile, BK=64, 4 waves (2x2),
// SINGLE-buffered swizzled LDS (32 KiB) -> 3 blocks/CU via launch_bounds(256,3).
// Per K-step: load_a(t+1)->regs | compute(t) | barrier | gld_lds B(t+1) + write_a | barrier.
__global__ __launch_bounds__(256, 3)
void gemm_fused(const float* __restrict__ X, const u16* __restrict__ Bw,
                const float* __restrict__ bias, float* __restrict__ Y) {
    // XCD-aware bijective swizzle: 2352 blocks = 8 * 294
    const int b = blockIdx.x;
    const int bid = (b & 7) * 294 + (b >> 3);
    const int mt = bid / 6, nt = bid - mt * 6;
    const int m0 = mt * 128, n0 = nt * 128;

    const int tid = threadIdx.x;
    const int lane = tid & 63;
    const int w = tid >> 6;
    const int wm = w >> 1, wn = w & 1;

    // LDS: logical [row][kb 0..127 bytes], physical byte = kb ^ ((row&7)<<4)
    __shared__ u16 As[128 * 64];
    __shared__ u16 Bs[128 * 64];

    f32x4 acc[4][4];
    #pragma unroll
    for (int i = 0; i < 4; ++i)
        #pragma unroll
        for (int j = 0; j < 4; ++j)
            acc[i][j] = (f32x4){0.f, 0.f, 0.f, 0.f};

    const int arow = tid >> 4;      // 0..15
    const int agg  = tid & 15;      // 16B fp32 granule within row
    const int bg = lane & 7;

    float4 R[8];

    auto load_a = [&](int k0) {
        const float4* src = (const float4*)(X + (long)m0 * K_DIM + k0);
        #pragma unroll
        for (int i = 0; i < 8; ++i) {
            int r = arow + 16 * i;
            R[i] = src[(long)r * (K_DIM / 4) + agg];
        }
    };

    auto write_a = [&]() {
        #pragma unroll
        for (int i = 0; i < 8; ++i) {
            int r = arow + 16 * i;
            int pb = (agg * 8) ^ ((r & 7) << 4);   // bf16 byte offset in row
            u16x4 hv;
            hv.x = f2bf(R[i].x);
            hv.y = f2bf(R[i].y);
            hv.z = f2bf(R[i].z);
            hv.w = f2bf(R[i].w);
            *(u16x4*)&As[r * 64 + (pb >> 1)] = hv;
        }
    };

    auto stage_b = [&](int k0) {
        #pragma unroll
        for (int j = 0; j < 4; ++j) {
            int rowbase = j * 32 + w * 8;
            int row = rowbase + (lane >> 3);
            // pre-swizzled global source, linear LDS dest (base + lane*16)
            const char* src = (const char*)Bw + ((long)(n0 + row) * K_DIM + k0) * 2 +
                              ((bg * 16) ^ ((row & 7) << 4));
            gld_lds16(src, (void*)&Bs[rowbase * 64]);
        }
    };

    auto compute = [&]() {
        #pragma unroll
        for (int h = 0; h < 2; ++h) {
            bf16x8 av[4], bv_[4];
            #pragma unroll
            for (int mf = 0; mf < 4; ++mf) {
                int r = wm * 64 + mf * 16 + (lane & 15);
                int pb = (h * 64 + ((lane >> 4) << 4)) ^ ((r & 7) << 4);
                av[mf] = *(const bf16x8*)&As[r * 64 + (pb >> 1)];
            }
            #pragma unroll
            for (int nf = 0; nf < 4; ++nf) {
                int r = wn * 64 + nf * 16 + (lane & 15);
                int pb = (h * 64 + ((lane >> 4) << 4)) ^ ((r & 7) << 4);
                bv_[nf] = *(const bf16x8*)&Bs[r * 64 + (pb >> 1)];
            }
            __builtin_amdgcn_s_setprio(1);
            #pragma unroll
            for (int mf = 0; mf < 4; ++mf)
                #pragma unroll
                for (int nf = 0; nf < 4; ++nf)
                    acc[mf][nf] = __builtin_amdgcn_mfma_f32_16x16x32_bf16(
                        av[mf], bv_[nf], acc[mf][nf], 0, 0, 0);
            __builtin_amdgcn_s_setprio(0);
        }
    };

    // ---- prologue: stage tile 0 ----
    load_a(0);
    stage_b(0);
    write_a();            // waits only on the 8 A loads; gld_lds stays in flight
    __syncthreads();      // drains gld_lds B0; tile 0 staged

    const int NT = K_DIM / 64;  // 12
    #pragma unroll 1
    for (int t = 0; t < NT - 1; ++t) {
        load_a((t + 1) * 64);   // issue next A loads; latency hidden under compute
        compute();
        __syncthreads();        // all waves done reading As/Bs
        stage_b((t + 1) * 64);  // issue gld_lds into freed buffer
        write_a();              // cvt+ds_write A(t+1); A-regs drained by barrier above
        __syncthreads();        // staging visible (drains gld_lds)
    }
    compute();                  // tile 11

    // epilogue: C/D layout col=lane&15, row=(lane>>4)*4+reg
    const int colq = lane & 15;
    const int rowq = (lane >> 4) * 4;
    #pragma unroll
    for (int nf = 0; nf < 4; ++nf) {
        int col = n0 + wn * 64 + nf * 16 + colq;
        float bi = bias[col];
        #pragma unroll
        for (int mf = 0; mf < 4; ++mf) {
            long rbase = m0 + wm * 64 + mf * 16 + rowq;
            #pragma unroll
            for (int r = 0; r < 4; ++r) {
                __builtin_nontemporal_store(acc[mf][nf][r] + bi,
                                            &Y[(rbase + r) * N_DIM + col]);
            }
        }
    }
}

extern "C" void kernel_launch(void* const* d_in, const int* in_sizes, int n_in,
                              void* d_out, int out_size, void* d_ws, size_t ws_size,
                              hipStream_t stream) {
    const float* x      = (const float*)d_in[0];
    const float* qkv_w  = (const float*)d_in[1];
    const float* qkv_b  = (const float*)d_in[2];
    const float* proj_w = (const float*)d_in[3];
    const float* proj_b = (const float*)d_in[4];
    const float* pe     = (const float*)d_in[5];
    float* y = (float*)d_out;

    u16*   Bw   = (u16*)d_ws;
    float* bias = (float*)((char*)d_ws + (size_t)N_DIM * K_DIM * 2);

    fold_weights<<<768, 256, 0, stream>>>(qkv_w, qkv_b, proj_w, proj_b, pe, Bw, bias);
    gemm_fused<<<(M_DIM / 128) * (N_DIM / 128), 256, 0, stream>>>(x, Bw, bias, y);
}